// Round 1
// baseline (155.102 us; speedup 1.0000x reference)
//
#include <hip/hip_runtime.h>

#define DIM 128
#define NGRAPH 4096
#define NSTEM 81920
#define NJROW 81920
#define NOUT 105
#define COLS 2111           // 1 stop + 10 break + 2100 add
#define STEMS_PER_GRAPH 20
#define ROWS_PER_BLOCK 64
#define LDSPAD 132          // 128 + 4: keeps 16B alignment, breaks bank aliasing

__device__ __forceinline__ float lrelu(float v) {
    return v > 0.f ? v : 0.01f * v;
}

// ---------------- stem MLP: gather -> 128x128 -> lrelu -> 128x105 -> scatter
__global__ __launch_bounds__(256) void stem_kernel(
    const float* __restrict__ atom, const int* __restrict__ sidx,
    const float* __restrict__ W1, const float* __restrict__ b1,
    const float* __restrict__ W2, const float* __restrict__ b2,
    float* __restrict__ out)
{
    __shared__ float Xs[ROWS_PER_BLOCK][LDSPAD];
    const int tid  = threadIdx.x;
    const int base = blockIdx.x * ROWS_PER_BLOCK;

    // gather 64 rows of 128 f32 (coalesced: consecutive tid -> consecutive k)
    #pragma unroll
    for (int i = 0; i < 32; ++i) {
        int e = i * 256 + tid;
        int r = e >> 7, k = e & 127;
        int a = sidx[base + r];
        Xs[r][k] = atom[a * DIM + k];
    }
    __syncthreads();

    const int ts = tid >> 4;   // 0..15 : group of 4 stems
    const int tj = tid & 15;   // 0..15 : 8 output cols

    // ---- layer 1: acc[stem 0..3][j 0..7]
    float acc[4][8];
    #pragma unroll
    for (int i = 0; i < 4; ++i)
        #pragma unroll
        for (int u = 0; u < 8; ++u) acc[i][u] = b1[tj * 8 + u];

    for (int k = 0; k < DIM; k += 4) {
        float x4[4][4];
        #pragma unroll
        for (int i = 0; i < 4; ++i)
            *(float4*)x4[i] = *(const float4*)&Xs[ts * 4 + i][k];
        #pragma unroll
        for (int kk = 0; kk < 4; ++kk) {
            float4 wa = *(const float4*)(W1 + (k + kk) * DIM + tj * 8);
            float4 wb = *(const float4*)(W1 + (k + kk) * DIM + tj * 8 + 4);
            float w[8] = {wa.x, wa.y, wa.z, wa.w, wb.x, wb.y, wb.z, wb.w};
            #pragma unroll
            for (int i = 0; i < 4; ++i) {
                float xf = x4[i][kk];
                #pragma unroll
                for (int u = 0; u < 8; ++u) acc[i][u] += xf * w[u];
            }
        }
    }

    // all layer-1 reads of Xs done -> overwrite with H
    __syncthreads();
    #pragma unroll
    for (int i = 0; i < 4; ++i) {
        float4 h0, h1;
        h0.x = lrelu(acc[i][0]); h0.y = lrelu(acc[i][1]);
        h0.z = lrelu(acc[i][2]); h0.w = lrelu(acc[i][3]);
        h1.x = lrelu(acc[i][4]); h1.y = lrelu(acc[i][5]);
        h1.z = lrelu(acc[i][6]); h1.w = lrelu(acc[i][7]);
        *(float4*)&Xs[ts * 4 + i][tj * 8]     = h0;
        *(float4*)&Xs[ts * 4 + i][tj * 8 + 4] = h1;
    }
    __syncthreads();

    // ---- layer 2: wave handles 16 stems (2 groups of 8); lane -> cols (c, c+64)
    const int wv = tid >> 6, lane = tid & 63;
    const int c0 = lane, c1 = lane + 64;
    const bool has1 = (c1 < NOUT);
    const float bb0 = b2[c0];
    const float bb1 = has1 ? b2[c1] : 0.f;

    for (int g2 = 0; g2 < 2; ++g2) {
        const int s0 = wv * 16 + g2 * 8;
        float a0[8], a1[8];
        #pragma unroll
        for (int i = 0; i < 8; ++i) { a0[i] = bb0; a1[i] = bb1; }

        for (int k = 0; k < DIM; k += 4) {
            float h4[8][4];
            #pragma unroll
            for (int i = 0; i < 8; ++i)
                *(float4*)h4[i] = *(const float4*)&Xs[s0 + i][k];
            #pragma unroll
            for (int kk = 0; kk < 4; ++kk) {
                float w0 = W2[(k + kk) * NOUT + c0];
                float w1 = has1 ? W2[(k + kk) * NOUT + c1] : 0.f;
                #pragma unroll
                for (int i = 0; i < 8; ++i) {
                    a0[i] += h4[i][kk] * w0;
                    a1[i] += h4[i][kk] * w1;
                }
            }
        }
        #pragma unroll
        for (int i = 0; i < 8; ++i) {
            int S   = base + s0 + i;
            int gph = S / STEMS_PER_GRAPH;
            int sl  = S - gph * STEMS_PER_GRAPH;
            int ob  = NGRAPH + gph * COLS + 1 + 10 + sl * NOUT;
            out[ob + c0] = a0[i];
            if (has1) out[ob + c1] = a1[i];
        }
    }
}

// ---------------- jbond MLP: gather -> 128x128 -> lrelu -> dot(128) -> pair mean
__global__ __launch_bounds__(256) void jbond_kernel(
    const float* __restrict__ atom, const int* __restrict__ jidx,
    const float* __restrict__ W1, const float* __restrict__ b1,
    const float* __restrict__ W2, const float* __restrict__ b2,
    float* __restrict__ out)
{
    __shared__ float Xs[ROWS_PER_BLOCK][LDSPAD];
    const int tid  = threadIdx.x;
    const int base = blockIdx.x * ROWS_PER_BLOCK;

    #pragma unroll
    for (int i = 0; i < 32; ++i) {
        int e = i * 256 + tid;
        int r = e >> 7, k = e & 127;
        int a = jidx[base + r];
        Xs[r][k] = atom[a * DIM + k];
    }
    __syncthreads();

    const int ts = tid >> 4;
    const int tj = tid & 15;

    float acc[4][8];
    #pragma unroll
    for (int i = 0; i < 4; ++i)
        #pragma unroll
        for (int u = 0; u < 8; ++u) acc[i][u] = b1[tj * 8 + u];

    for (int k = 0; k < DIM; k += 4) {
        float x4[4][4];
        #pragma unroll
        for (int i = 0; i < 4; ++i)
            *(float4*)x4[i] = *(const float4*)&Xs[ts * 4 + i][k];
        #pragma unroll
        for (int kk = 0; kk < 4; ++kk) {
            float4 wa = *(const float4*)(W1 + (k + kk) * DIM + tj * 8);
            float4 wb = *(const float4*)(W1 + (k + kk) * DIM + tj * 8 + 4);
            float w[8] = {wa.x, wa.y, wa.z, wa.w, wb.x, wb.y, wb.z, wb.w};
            #pragma unroll
            for (int i = 0; i < 4; ++i) {
                float xf = x4[i][kk];
                #pragma unroll
                for (int u = 0; u < 8; ++u) acc[i][u] += xf * w[u];
            }
        }
    }

    // layer 2: per-thread partial dot over its 8 j's, shuffle-reduce over 16 tj lanes
    float4 wva = *(const float4*)(W2 + tj * 8);
    float4 wvb = *(const float4*)(W2 + tj * 8 + 4);
    float w2r[8] = {wva.x, wva.y, wva.z, wva.w, wvb.x, wvb.y, wvb.z, wvb.w};

    float part[4];
    #pragma unroll
    for (int i = 0; i < 4; ++i) {
        float p = 0.f;
        #pragma unroll
        for (int u = 0; u < 8; ++u) p += lrelu(acc[i][u]) * w2r[u];
        part[i] = p;
    }
    #pragma unroll
    for (int off = 1; off < 16; off <<= 1) {
        #pragma unroll
        for (int i = 0; i < 4; ++i)
            part[i] += __shfl_xor(part[i], off, 64);
    }

    if (tj == 0) {
        const float bb = b2[0];
        float v0 = (part[0] + part[1]) * 0.5f + bb;
        float v1 = (part[2] + part[3]) * 0.5f + bb;
        int B0 = (base + ts * 4) >> 1;  // bond index, and B0+1
        int g0 = B0 / 10, col0 = B0 - g0 * 10;
        int B1 = B0 + 1;
        int g1 = B1 / 10, col1 = B1 - g1 * 10;
        out[NGRAPH + g0 * COLS + 1 + col0] = v0;
        out[NGRAPH + g1 * COLS + 1 + col1] = v1;
    }
}

// ---------------- value copy + stop logit
__global__ __launch_bounds__(256) void scalar_kernel(
    const float* __restrict__ so, float* __restrict__ out)
{
    int g = blockIdx.x * 256 + threadIdx.x;
    if (g < NGRAPH) {
        out[g] = so[2 * g];
        out[NGRAPH + g * COLS] = so[2 * g + 1];
    }
}

extern "C" void kernel_launch(void* const* d_in, const int* in_sizes, int n_in,
                              void* d_out, int out_size, void* d_ws, size_t ws_size,
                              hipStream_t stream) {
    const float* per_atom_out = (const float*)d_in[0];
    const float* scalar_outs  = (const float*)d_in[1];
    const int*   stem_atmidx  = (const int*)d_in[2];
    const int*   jbond_atmidx = (const int*)d_in[3];
    // d_in[4] = num_graphs (constant 4096)
    const float* W1s = (const float*)d_in[5];
    const float* b1s = (const float*)d_in[6];
    const float* W2s = (const float*)d_in[7];
    const float* b2s = (const float*)d_in[8];
    const float* W1j = (const float*)d_in[9];
    const float* b1j = (const float*)d_in[10];
    const float* W2j = (const float*)d_in[11];
    const float* b2j = (const float*)d_in[12];
    float* out = (float*)d_out;

    hipLaunchKernelGGL(stem_kernel, dim3(NSTEM / ROWS_PER_BLOCK), dim3(256), 0, stream,
                       per_atom_out, stem_atmidx, W1s, b1s, W2s, b2s, out);
    hipLaunchKernelGGL(jbond_kernel, dim3(NJROW / ROWS_PER_BLOCK), dim3(256), 0, stream,
                       per_atom_out, jbond_atmidx, W1j, b1j, W2j, b2j, out);
    hipLaunchKernelGGL(scalar_kernel, dim3((NGRAPH + 255) / 256), dim3(256), 0, stream,
                       scalar_outs, out);
}

// Round 2
// 59.147 us; speedup vs baseline: 2.6223x; 2.6223x over previous
//
#include <hip/hip_runtime.h>

#define DIM 128
#define NGRAPH 4096
#define NSTEM 81920
#define NJROW 81920
#define NOUT 105
#define COLS 2111           // 1 stop + 10 break + 2100 add
#define STEMS_PER_GRAPH 20
#define ROWS_PER_BLOCK 64
#define XPAD 136            // shorts: 272B row stride -> rows step 4 banks, 2 lanes/bank on A-frag reads

typedef __attribute__((ext_vector_type(8))) short bf16x8;
typedef __attribute__((ext_vector_type(4))) float f32x4;

__device__ __forceinline__ unsigned short f2bf(float f) {
    unsigned int u = __builtin_bit_cast(unsigned int, f);
    return (unsigned short)((u + 0x7fffu + ((u >> 16) & 1u)) >> 16);  // RNE
}
__device__ __forceinline__ float lrelu(float v) { return v > 0.f ? v : 0.01f * v; }

// ---- pack weights into MFMA B-fragment order (bf16), zero-padded cols:
// packed[((kt*NT+nt)*64+lane)*8+i] = bf16( W[(kt*32+(lane>>4)*8+i)][nt*16+(lane&15)] )
// ws layout (shorts): W1s @0 (4*8*512=16384), W2s @16384 (4*7*512=14336), W1j @30720 (16384)
__global__ __launch_bounds__(256) void pack_weights(
    const float* __restrict__ W1s, const float* __restrict__ W2s,
    const float* __restrict__ W1j, short* __restrict__ ws)
{
    int b = blockIdx.x;
    const float* W; short* dst; int NT, N;
    if (b == 0)      { W = W1s; dst = ws;         NT = 8; N = 128; }
    else if (b == 1) { W = W2s; dst = ws + 16384; NT = 7; N = 105; }
    else             { W = W1j; dst = ws + 30720; NT = 8; N = 128; }
    int total = 4 * NT * 512;
    for (int idx = threadIdx.x; idx < total; idx += 256) {
        int i = idx & 7, lane = (idx >> 3) & 63, f = idx >> 9;
        int nt = f % NT, kt = f / NT;
        int k = kt * 32 + ((lane >> 4) << 3) + i;
        int n = nt * 16 + (lane & 15);
        float v = (n < N) ? W[k * N + n] : 0.f;
        dst[idx] = (short)f2bf(v);
    }
}

// ---- stem MLP via MFMA: gather->bf16 LDS; L1 = X(64x128)*W1; lrelu; L2 = H*W2(128x112pad)
__global__ __launch_bounds__(256) void stem_mfma(
    const float* __restrict__ atom, const int* __restrict__ sidx,
    const short* __restrict__ W1p, const float* __restrict__ b1,
    const short* __restrict__ W2p, const float* __restrict__ b2,
    float* __restrict__ out)
{
    __shared__ short Xs[ROWS_PER_BLOCK][XPAD];
    const int tid  = threadIdx.x;
    const int base = blockIdx.x * ROWS_PER_BLOCK;
    const int w = tid >> 6, l = tid & 63;
    const int lq = l >> 4, lc = l & 15;

    // gather + convert: 8192 elems, 2/thread/iter (float2 -> packed 2xbf16, 4B LDS write)
    #pragma unroll
    for (int s = 0; s < 16; ++s) {
        int e = s * 512 + tid * 2;
        int r = e >> 7, k = e & 127;
        int a = sidx[base + r];
        float2 v = *(const float2*)(atom + a * DIM + k);
        unsigned int pk = ((unsigned int)f2bf(v.y) << 16) | f2bf(v.x);
        *(unsigned int*)&Xs[r][k] = pk;
    }
    __syncthreads();

    // ---- layer 1: wave w owns rows [w*16, w*16+16)
    f32x4 acc[8];
    #pragma unroll
    for (int nt = 0; nt < 8; ++nt) {
        float bb = b1[nt * 16 + lc];
        acc[nt] = (f32x4){bb, bb, bb, bb};
    }
    #pragma unroll
    for (int kt = 0; kt < 4; ++kt) {
        bf16x8 af = *(const bf16x8*)&Xs[w * 16 + lc][kt * 32 + lq * 8];
        #pragma unroll
        for (int nt = 0; nt < 8; ++nt) {
            bf16x8 bfg = *(const bf16x8*)(W1p + ((kt * 8 + nt) * 64 + l) * 8);
            acc[nt] = __builtin_amdgcn_mfma_f32_16x16x32_bf16(af, bfg, acc[nt], 0, 0, 0);
        }
    }

    // H -> LDS, bf16. Wave-private rows: compiler's lgkmcnt ordering suffices, no barrier.
    // D layout: row = lq*4+rg, col = nt*16+lc
    #pragma unroll
    for (int nt = 0; nt < 8; ++nt)
        #pragma unroll
        for (int rg = 0; rg < 4; ++rg)
            Xs[w * 16 + lq * 4 + rg][nt * 16 + lc] = (short)f2bf(lrelu(acc[nt][rg]));

    // ---- layer 2: H(16x128) * W2(128x112, cols>=105 zero)
    f32x4 acc2[7];
    #pragma unroll
    for (int nt = 0; nt < 7; ++nt) {
        int c = nt * 16 + lc;
        float bb = (c < NOUT) ? b2[c] : 0.f;
        acc2[nt] = (f32x4){bb, bb, bb, bb};
    }
    #pragma unroll
    for (int kt = 0; kt < 4; ++kt) {
        bf16x8 af = *(const bf16x8*)&Xs[w * 16 + lc][kt * 32 + lq * 8];
        #pragma unroll
        for (int nt = 0; nt < 7; ++nt) {
            bf16x8 bfg = *(const bf16x8*)(W2p + ((kt * 7 + nt) * 64 + l) * 8);
            acc2[nt] = __builtin_amdgcn_mfma_f32_16x16x32_bf16(af, bfg, acc2[nt], 0, 0, 0);
        }
    }

    // epilogue: scatter into add_logits window
    #pragma unroll
    for (int rg = 0; rg < 4; ++rg) {
        int S = base + w * 16 + lq * 4 + rg;
        int gph = S / STEMS_PER_GRAPH, sl = S - gph * STEMS_PER_GRAPH;
        float* ob = out + NGRAPH + gph * COLS + 1 + 10 + sl * NOUT;
        #pragma unroll
        for (int nt = 0; nt < 7; ++nt) {
            int c = nt * 16 + lc;
            if (c < NOUT) ob[c] = acc2[nt][rg];
        }
    }
}

// ---- jbond MLP: L1 via MFMA, L2 (128->1) in-register + shfl reduce, pair mean
__global__ __launch_bounds__(256) void jbond_mfma(
    const float* __restrict__ atom, const int* __restrict__ jidx,
    const short* __restrict__ W1p, const float* __restrict__ b1,
    const float* __restrict__ W2, const float* __restrict__ b2,
    float* __restrict__ out)
{
    __shared__ short Xs[ROWS_PER_BLOCK][XPAD];
    const int tid  = threadIdx.x;
    const int base = blockIdx.x * ROWS_PER_BLOCK;
    const int w = tid >> 6, l = tid & 63;
    const int lq = l >> 4, lc = l & 15;

    #pragma unroll
    for (int s = 0; s < 16; ++s) {
        int e = s * 512 + tid * 2;
        int r = e >> 7, k = e & 127;
        int a = jidx[base + r];
        float2 v = *(const float2*)(atom + a * DIM + k);
        unsigned int pk = ((unsigned int)f2bf(v.y) << 16) | f2bf(v.x);
        *(unsigned int*)&Xs[r][k] = pk;
    }
    __syncthreads();

    f32x4 acc[8];
    #pragma unroll
    for (int nt = 0; nt < 8; ++nt) {
        float bb = b1[nt * 16 + lc];
        acc[nt] = (f32x4){bb, bb, bb, bb};
    }
    #pragma unroll
    for (int kt = 0; kt < 4; ++kt) {
        bf16x8 af = *(const bf16x8*)&Xs[w * 16 + lc][kt * 32 + lq * 8];
        #pragma unroll
        for (int nt = 0; nt < 8; ++nt) {
            bf16x8 bfg = *(const bf16x8*)(W1p + ((kt * 8 + nt) * 64 + l) * 8);
            acc[nt] = __builtin_amdgcn_mfma_f32_16x16x32_bf16(af, bfg, acc[nt], 0, 0, 0);
        }
    }

    // layer 2: p[rg] = sum_c lrelu(H[row,c]) * W2[c]; lane holds cols nt*16+lc
    float p0 = 0.f, p1 = 0.f, p2 = 0.f, p3 = 0.f;
    #pragma unroll
    for (int nt = 0; nt < 8; ++nt) {
        float wv = W2[nt * 16 + lc];
        p0 += lrelu(acc[nt][0]) * wv;
        p1 += lrelu(acc[nt][1]) * wv;
        p2 += lrelu(acc[nt][2]) * wv;
        p3 += lrelu(acc[nt][3]) * wv;
    }
    #pragma unroll
    for (int off = 1; off < 16; off <<= 1) {
        p0 += __shfl_xor(p0, off, 64);
        p1 += __shfl_xor(p1, off, 64);
        p2 += __shfl_xor(p2, off, 64);
        p3 += __shfl_xor(p3, off, 64);
    }
    if (lc == 0) {
        float bb = b2[0];
        int row0 = base + w * 16 + lq * 4;       // rows row0..row0+3 (even)
        int B0 = row0 >> 1;                       // bond of rows (row0, row0+1)
        int B1 = B0 + 1;                          // bond of rows (row0+2, row0+3)
        float v0 = (p0 + p1) * 0.5f + bb;
        float v1 = (p2 + p3) * 0.5f + bb;
        int g0 = B0 / 10, c0 = B0 - g0 * 10;
        int g1 = B1 / 10, c1 = B1 - g1 * 10;
        out[NGRAPH + g0 * COLS + 1 + c0] = v0;
        out[NGRAPH + g1 * COLS + 1 + c1] = v1;
    }
}

// ---- value copy + stop logit
__global__ __launch_bounds__(256) void scalar_kernel(
    const float* __restrict__ so, float* __restrict__ out)
{
    int g = blockIdx.x * 256 + threadIdx.x;
    if (g < NGRAPH) {
        out[g] = so[2 * g];
        out[NGRAPH + g * COLS] = so[2 * g + 1];
    }
}

extern "C" void kernel_launch(void* const* d_in, const int* in_sizes, int n_in,
                              void* d_out, int out_size, void* d_ws, size_t ws_size,
                              hipStream_t stream) {
    const float* per_atom_out = (const float*)d_in[0];
    const float* scalar_outs  = (const float*)d_in[1];
    const int*   stem_atmidx  = (const int*)d_in[2];
    const int*   jbond_atmidx = (const int*)d_in[3];
    const float* W1s = (const float*)d_in[5];
    const float* b1s = (const float*)d_in[6];
    const float* W2s = (const float*)d_in[7];
    const float* b2s = (const float*)d_in[8];
    const float* W1j = (const float*)d_in[9];
    const float* b1j = (const float*)d_in[10];
    const float* W2j = (const float*)d_in[11];
    const float* b2j = (const float*)d_in[12];
    float* out = (float*)d_out;
    short* wsp = (short*)d_ws;   // needs 92 KB

    hipLaunchKernelGGL(pack_weights, dim3(3), dim3(256), 0, stream, W1s, W2s, W1j, wsp);
    hipLaunchKernelGGL(scalar_kernel, dim3((NGRAPH + 255) / 256), dim3(256), 0, stream,
                       scalar_outs, out);
    hipLaunchKernelGGL(stem_mfma, dim3(NSTEM / ROWS_PER_BLOCK), dim3(256), 0, stream,
                       per_atom_out, stem_atmidx, wsp, b1s, wsp + 16384, b2s, out);
    hipLaunchKernelGGL(jbond_mfma, dim3(NJROW / ROWS_PER_BLOCK), dim3(256), 0, stream,
                       per_atom_out, jbond_atmidx, wsp + 30720, b1j, W2j, b2j, out);
}

// Round 3
// 51.704 us; speedup vs baseline: 2.9998x; 1.1439x over previous
//
#include <hip/hip_runtime.h>

#define DIM 128
#define NGRAPH 4096
#define NSTEM 81920
#define NJROW 81920
#define NOUT 105
#define COLS 2111           // 1 stop + 10 break + 2100 add
#define STEMS_PER_GRAPH 20
#define ROWS 64
#define XPAD 136            // shorts: 272B row stride; A-frag b128 reads are conflict-free
#define NBLK_STEM (NSTEM / ROWS)
#define NBLK_JB   (NJROW / ROWS)

typedef __attribute__((ext_vector_type(8))) short bf16x8;
typedef __attribute__((ext_vector_type(4))) float f32x4;

__device__ __forceinline__ unsigned short f2bf(float f) {
    unsigned int u = __builtin_bit_cast(unsigned int, f);
    return (unsigned short)((u + 0x7fffu + ((u >> 16) & 1u)) >> 16);  // RNE
}
__device__ __forceinline__ float lrelu(float v) { return v > 0.f ? v : 0.01f * v; }

// ---- prep: pack weights to MFMA B-frag order (blocks 0-2) + scalar outs (blocks 3-18)
// packed[((kt*NT+nt)*64+lane)*8+i] = bf16( W[(kt*32+(lane>>4)*8+i)][nt*16+(lane&15)] )
// ws layout (shorts): W1s @0 (16384), W2s @16384 (14336), W1j @30720 (16384)
__global__ __launch_bounds__(256) void prep_kernel(
    const float* __restrict__ W1s, const float* __restrict__ W2s,
    const float* __restrict__ W1j, const float* __restrict__ so,
    short* __restrict__ ws, float* __restrict__ out)
{
    int b = blockIdx.x;
    if (b < 3) {
        const float* W; short* dst; int NT, N;
        if (b == 0)      { W = W1s; dst = ws;         NT = 8; N = 128; }
        else if (b == 1) { W = W2s; dst = ws + 16384; NT = 7; N = 105; }
        else             { W = W1j; dst = ws + 30720; NT = 8; N = 128; }
        int total = 4 * NT * 512;
        for (int idx = threadIdx.x; idx < total; idx += 256) {
            int i = idx & 7, lane = (idx >> 3) & 63, f = idx >> 9;
            int nt = f % NT, kt = f / NT;
            int k = kt * 32 + ((lane >> 4) << 3) + i;
            int n = nt * 16 + (lane & 15);
            float v = (n < N) ? W[k * N + n] : 0.f;
            dst[idx] = (short)f2bf(v);
        }
    } else {
        int g = (b - 3) * 256 + threadIdx.x;
        if (g < NGRAPH) {
            out[g] = so[2 * g];
            out[NGRAPH + g * COLS] = so[2 * g + 1];
        }
    }
}

// ---- fused stem+jbond MLP. Column-split waves: wave w computes ALL 64 rows,
// cols [w*32, w*32+32). Each weight fragment read once per BLOCK (was once per wave).
__global__ __launch_bounds__(256) void fused_mlp(
    const float* __restrict__ atom,
    const int* __restrict__ sidx, const int* __restrict__ jidx,
    const short* __restrict__ wsp,
    const float* __restrict__ b1s, const float* __restrict__ b2s,
    const float* __restrict__ b1j,
    const float* __restrict__ W2j, const float* __restrict__ b2j,
    float* __restrict__ out)
{
    __shared__ short Xs[ROWS][XPAD];
    __shared__ float red[4][ROWS];
    const int tid = threadIdx.x;
    const bool isStem = blockIdx.x < NBLK_STEM;
    const int blk  = isStem ? blockIdx.x : blockIdx.x - NBLK_STEM;
    const int base = blk * ROWS;
    const int w = tid >> 6, l = tid & 63;
    const int lq = l >> 4, lc = l & 15;

    const int*   idx = isStem ? sidx : jidx;
    const short* W1p = isStem ? wsp : wsp + 30720;
    const float* b1  = isStem ? b1s : b1j;

    // gather + bf16 convert: 8192 elems, float4 per thread-iter (8B LDS write)
    #pragma unroll
    for (int s = 0; s < 8; ++s) {
        int e = s * 1024 + tid * 4;
        int r = e >> 7, k = e & 127;
        int a = idx[base + r];
        float4 v = *(const float4*)(atom + a * DIM + k);
        uint2 pk;
        pk.x = ((unsigned int)f2bf(v.y) << 16) | f2bf(v.x);
        pk.y = ((unsigned int)f2bf(v.w) << 16) | f2bf(v.z);
        *(uint2*)&Xs[r][k] = pk;
    }
    __syncthreads();

    // ---- layer 1: acc[m][j] = rows [m*16..m*16+16) x cols [(w*2+j)*16..+16)
    f32x4 acc[4][2];
    #pragma unroll
    for (int j = 0; j < 2; ++j) {
        float bb = b1[(w * 2 + j) * 16 + lc];
        #pragma unroll
        for (int m = 0; m < 4; ++m) acc[m][j] = (f32x4){bb, bb, bb, bb};
    }
    #pragma unroll
    for (int kt = 0; kt < 4; ++kt) {
        bf16x8 a0 = *(const bf16x8*)&Xs[lc]     [kt * 32 + lq * 8];
        bf16x8 a1 = *(const bf16x8*)&Xs[16 + lc][kt * 32 + lq * 8];
        bf16x8 a2 = *(const bf16x8*)&Xs[32 + lc][kt * 32 + lq * 8];
        bf16x8 a3 = *(const bf16x8*)&Xs[48 + lc][kt * 32 + lq * 8];
        #pragma unroll
        for (int j = 0; j < 2; ++j) {
            bf16x8 bfg = *(const bf16x8*)(W1p + ((kt * 8 + w * 2 + j) * 64 + l) * 8);
            acc[0][j] = __builtin_amdgcn_mfma_f32_16x16x32_bf16(a0, bfg, acc[0][j], 0, 0, 0);
            acc[1][j] = __builtin_amdgcn_mfma_f32_16x16x32_bf16(a1, bfg, acc[1][j], 0, 0, 0);
            acc[2][j] = __builtin_amdgcn_mfma_f32_16x16x32_bf16(a2, bfg, acc[2][j], 0, 0, 0);
            acc[3][j] = __builtin_amdgcn_mfma_f32_16x16x32_bf16(a3, bfg, acc[3][j], 0, 0, 0);
        }
    }

    if (isStem) {
        __syncthreads();   // all waves done reading X A-frags
        // H -> LDS (bf16, lrelu). D layout: row = m*16+lq*4+rg, col = (w*2+j)*16+lc
        #pragma unroll
        for (int j = 0; j < 2; ++j)
            #pragma unroll
            for (int m = 0; m < 4; ++m)
                #pragma unroll
                for (int rg = 0; rg < 4; ++rg)
                    Xs[m * 16 + lq * 4 + rg][(w * 2 + j) * 16 + lc] =
                        (short)f2bf(lrelu(acc[m][j][rg]));
        __syncthreads();

        // ---- layer 2: H(64x128) x W2(128x112pad); wave w -> nt = w*2+j (nt=7 masked)
        const short* W2p = wsp + 16384;
        f32x4 acc2[4][2];
        #pragma unroll
        for (int j = 0; j < 2; ++j) {
            int c = (w * 2 + j) * 16 + lc;
            float bb = (c < NOUT) ? b2s[c] : 0.f;
            #pragma unroll
            for (int m = 0; m < 4; ++m) acc2[m][j] = (f32x4){bb, bb, bb, bb};
        }
        #pragma unroll
        for (int kt = 0; kt < 4; ++kt) {
            bf16x8 a0 = *(const bf16x8*)&Xs[lc]     [kt * 32 + lq * 8];
            bf16x8 a1 = *(const bf16x8*)&Xs[16 + lc][kt * 32 + lq * 8];
            bf16x8 a2 = *(const bf16x8*)&Xs[32 + lc][kt * 32 + lq * 8];
            bf16x8 a3 = *(const bf16x8*)&Xs[48 + lc][kt * 32 + lq * 8];
            #pragma unroll
            for (int j = 0; j < 2; ++j) {
                int nt = w * 2 + j;                 // nt==7: wasted MFMAs, writes masked
                bf16x8 bfg = *(const bf16x8*)(W2p + ((kt * 7 + nt) * 64 + l) * 8);
                acc2[0][j] = __builtin_amdgcn_mfma_f32_16x16x32_bf16(a0, bfg, acc2[0][j], 0, 0, 0);
                acc2[1][j] = __builtin_amdgcn_mfma_f32_16x16x32_bf16(a1, bfg, acc2[1][j], 0, 0, 0);
                acc2[2][j] = __builtin_amdgcn_mfma_f32_16x16x32_bf16(a2, bfg, acc2[2][j], 0, 0, 0);
                acc2[3][j] = __builtin_amdgcn_mfma_f32_16x16x32_bf16(a3, bfg, acc2[3][j], 0, 0, 0);
            }
        }
        // epilogue scatter
        #pragma unroll
        for (int m = 0; m < 4; ++m)
            #pragma unroll
            for (int rg = 0; rg < 4; ++rg) {
                int S = base + m * 16 + lq * 4 + rg;
                int gph = S / STEMS_PER_GRAPH, sl = S - gph * STEMS_PER_GRAPH;
                float* ob = out + NGRAPH + gph * COLS + 1 + 10 + sl * NOUT;
                #pragma unroll
                for (int j = 0; j < 2; ++j) {
                    int c = (w * 2 + j) * 16 + lc;
                    if (c < NOUT) ob[c] = acc2[m][j][rg];
                }
            }
    } else {
        // ---- jbond layer 2: dot with W2j over this wave's 32 cols, cross-wave reduce
        float wv0 = W2j[(w * 2) * 16 + lc];
        float wv1 = W2j[(w * 2 + 1) * 16 + lc];
        float pf[4][4];
        #pragma unroll
        for (int m = 0; m < 4; ++m)
            #pragma unroll
            for (int rg = 0; rg < 4; ++rg)
                pf[m][rg] = lrelu(acc[m][0][rg]) * wv0 + lrelu(acc[m][1][rg]) * wv1;
        #pragma unroll
        for (int off = 1; off < 16; off <<= 1)
            #pragma unroll
            for (int m = 0; m < 4; ++m)
                #pragma unroll
                for (int rg = 0; rg < 4; ++rg)
                    pf[m][rg] += __shfl_xor(pf[m][rg], off, 64);
        if (lc == 0)
            #pragma unroll
            for (int m = 0; m < 4; ++m)
                #pragma unroll
                for (int rg = 0; rg < 4; ++rg)
                    red[w][m * 16 + lq * 4 + rg] = pf[m][rg];
        __syncthreads();
        if (tid < 32) {
            int r0 = tid * 2;
            float s0 = red[0][r0] + red[1][r0] + red[2][r0] + red[3][r0];
            float s1 = red[0][r0 + 1] + red[1][r0 + 1] + red[2][r0 + 1] + red[3][r0 + 1];
            float v = (s0 + s1) * 0.5f + b2j[0];
            int B = blk * 32 + tid;
            int g = B / 10, c = B - g * 10;
            out[NGRAPH + g * COLS + 1 + c] = v;
        }
    }
}

extern "C" void kernel_launch(void* const* d_in, const int* in_sizes, int n_in,
                              void* d_out, int out_size, void* d_ws, size_t ws_size,
                              hipStream_t stream) {
    const float* per_atom_out = (const float*)d_in[0];
    const float* scalar_outs  = (const float*)d_in[1];
    const int*   stem_atmidx  = (const int*)d_in[2];
    const int*   jbond_atmidx = (const int*)d_in[3];
    const float* W1s = (const float*)d_in[5];
    const float* b1s = (const float*)d_in[6];
    const float* W2s = (const float*)d_in[7];
    const float* b2s = (const float*)d_in[8];
    const float* W1j = (const float*)d_in[9];
    const float* b1j = (const float*)d_in[10];
    const float* W2j = (const float*)d_in[11];
    const float* b2j = (const float*)d_in[12];
    float* out = (float*)d_out;
    short* wsp = (short*)d_ws;   // needs 94208 B

    hipLaunchKernelGGL(prep_kernel, dim3(19), dim3(256), 0, stream,
                       W1s, W2s, W1j, scalar_outs, wsp, out);
    hipLaunchKernelGGL(fused_mlp, dim3(NBLK_STEM + NBLK_JB), dim3(256), 0, stream,
                       per_atom_out, stem_atmidx, jbond_atmidx, wsp,
                       b1s, b2s, b1j, W2j, b2j, out);
}

// Round 4
// 50.781 us; speedup vs baseline: 3.0543x; 1.0182x over previous
//
#include <hip/hip_runtime.h>

#define DIM 128
#define NGRAPH 4096
#define NSTEM 81920
#define NJROW 81920
#define NOUT 105
#define COLS 2111           // 1 stop + 10 break + 2100 add
#define SPG 20              // stems per graph
#define ROWS 64
#define XPAD 136            // shorts: 272B row stride; A-frag b128 reads ~2-way (free)
#define NBLK_STEM (NSTEM / ROWS)
#define NBLK_JB   (NJROW / ROWS)

typedef __attribute__((ext_vector_type(8))) short bf16x8;
typedef __attribute__((ext_vector_type(4))) float f32x4;

__device__ __forceinline__ unsigned short f2bf(float f) {
    unsigned int u = __builtin_bit_cast(unsigned int, f);
    return (unsigned short)((u + 0x7fffu + ((u >> 16) & 1u)) >> 16);  // RNE
}
__device__ __forceinline__ unsigned int pk2(float x, float y) {
    return ((unsigned int)f2bf(y) << 16) | f2bf(x);
}
__device__ __forceinline__ float lrelu(float v) { return v > 0.f ? v : 0.01f * v; }

// ---- prep: pack weights to MFMA B-frag order (blocks 0-2) + scalar outs (blocks 3-18)
// packed[((kt*NT+nt)*64+lane)*8+i] = bf16( W[(kt*32+(lane>>4)*8+i)][nt*16+(lane&15)] )
// ws layout (shorts): W1s @0 (16384), W2s @16384 (14336), W1j @30720 (16384)
__global__ __launch_bounds__(256) void prep_kernel(
    const float* __restrict__ W1s, const float* __restrict__ W2s,
    const float* __restrict__ W1j, const float* __restrict__ so,
    short* __restrict__ ws, float* __restrict__ out)
{
    int b = blockIdx.x;
    if (b < 3) {
        const float* W; short* dst; int NT, N;
        if (b == 0)      { W = W1s; dst = ws;         NT = 8; N = 128; }
        else if (b == 1) { W = W2s; dst = ws + 16384; NT = 7; N = 105; }
        else             { W = W1j; dst = ws + 30720; NT = 8; N = 128; }
        int total = 4 * NT * 512;
        for (int idx = threadIdx.x; idx < total; idx += 256) {
            int i = idx & 7, lane = (idx >> 3) & 63, f = idx >> 9;
            int nt = f % NT, kt = f / NT;
            int k = kt * 32 + ((lane >> 4) << 3) + i;
            int n = nt * 16 + (lane & 15);
            float v = (n < N) ? W[k * N + n] : 0.f;
            dst[idx] = (short)f2bf(v);
        }
    } else {
        int g = (b - 3) * 256 + threadIdx.x;
        if (g < NGRAPH) {
            out[g] = so[2 * g];
            out[NGRAPH + g * COLS] = so[2 * g + 1];
        }
    }
}

// ---- fused stem+jbond MLP. Column-split waves; ALL weight fragments preloaded
// into registers with loads issued during the gather's latency window, so the
// MFMA loops touch only LDS (A-frags) + registers (B-frags).
__global__ __launch_bounds__(256) void fused_mlp(
    const float* __restrict__ atom,
    const int* __restrict__ sidx, const int* __restrict__ jidx,
    const short* __restrict__ wsp,
    const float* __restrict__ b1s, const float* __restrict__ b2s,
    const float* __restrict__ b1j,
    const float* __restrict__ W2j, const float* __restrict__ b2j,
    float* __restrict__ out)
{
    __shared__ short Xs[ROWS][XPAD];
    __shared__ float red[4][ROWS];
    const int tid = threadIdx.x;
    const bool isStem = blockIdx.x < NBLK_STEM;
    const int blk  = isStem ? blockIdx.x : blockIdx.x - NBLK_STEM;
    const int base = blk * ROWS;
    const int w = tid >> 6, l = tid & 63;
    const int lq = l >> 4, lc = l & 15;

    const int*   idx = isStem ? sidx : jidx;
    const short* W1p = isStem ? wsp : wsp + 30720;
    const float* b1  = isStem ? b1s : b1j;

    // ---- (1) index loads, (2) gathers (longest latency, issue first),
    //      (3) weight/bias loads (L2-hot, complete under gather latency)
    const int rb = tid >> 4;         // row-in-quarter 0..15
    const int ko = (tid & 15) * 8;   // k offset 0..120
    int a0 = idx[base + rb];
    int a1 = idx[base + 16 + rb];
    int a2 = idx[base + 32 + rb];
    int a3 = idx[base + 48 + rb];

    float4 ga0 = *(const float4*)(atom + a0 * DIM + ko);
    float4 gb0 = *(const float4*)(atom + a0 * DIM + ko + 4);
    float4 ga1 = *(const float4*)(atom + a1 * DIM + ko);
    float4 gb1 = *(const float4*)(atom + a1 * DIM + ko + 4);
    float4 ga2 = *(const float4*)(atom + a2 * DIM + ko);
    float4 gb2 = *(const float4*)(atom + a2 * DIM + ko + 4);
    float4 ga3 = *(const float4*)(atom + a3 * DIM + ko);
    float4 gb3 = *(const float4*)(atom + a3 * DIM + ko + 4);

    bf16x8 wf1[4][2];
    #pragma unroll
    for (int kt = 0; kt < 4; ++kt)
        #pragma unroll
        for (int j = 0; j < 2; ++j)
            wf1[kt][j] = *(const bf16x8*)(W1p + ((kt * 8 + w * 2 + j) * 64 + l) * 8);

    float bb1[2];
    #pragma unroll
    for (int j = 0; j < 2; ++j) bb1[j] = b1[(w * 2 + j) * 16 + lc];

    bf16x8 wf2[4][2];
    float bb2[2];
    float wv0 = 0.f, wv1 = 0.f, bj = 0.f;
    if (isStem) {
        const short* W2p = wsp + 16384;
        #pragma unroll
        for (int kt = 0; kt < 4; ++kt)
            #pragma unroll
            for (int j = 0; j < 2; ++j) {
                int nt = w * 2 + j; if (nt > 6) nt = 6;   // clamp in-bounds; results masked
                wf2[kt][j] = *(const bf16x8*)(W2p + ((kt * 7 + nt) * 64 + l) * 8);
            }
        #pragma unroll
        for (int j = 0; j < 2; ++j) {
            int c = (w * 2 + j) * 16 + lc;
            bb2[j] = (c < NOUT) ? b2s[c] : 0.f;
        }
    } else {
        wv0 = W2j[(w * 2) * 16 + lc];
        wv1 = W2j[(w * 2 + 1) * 16 + lc];
        bj  = b2j[0];
    }

    // ---- convert + stage to LDS (one b128 write per row-slice)
    uint4 p;
    p.x = pk2(ga0.x, ga0.y); p.y = pk2(ga0.z, ga0.w);
    p.z = pk2(gb0.x, gb0.y); p.w = pk2(gb0.z, gb0.w);
    *(uint4*)&Xs[rb][ko] = p;
    p.x = pk2(ga1.x, ga1.y); p.y = pk2(ga1.z, ga1.w);
    p.z = pk2(gb1.x, gb1.y); p.w = pk2(gb1.z, gb1.w);
    *(uint4*)&Xs[16 + rb][ko] = p;
    p.x = pk2(ga2.x, ga2.y); p.y = pk2(ga2.z, ga2.w);
    p.z = pk2(gb2.x, gb2.y); p.w = pk2(gb2.z, gb2.w);
    *(uint4*)&Xs[32 + rb][ko] = p;
    p.x = pk2(ga3.x, ga3.y); p.y = pk2(ga3.z, ga3.w);
    p.z = pk2(gb3.x, gb3.y); p.w = pk2(gb3.z, gb3.w);
    *(uint4*)&Xs[48 + rb][ko] = p;
    __syncthreads();

    // ---- layer 1: acc[m][j] = rows [m*16..+16) x cols [(w*2+j)*16..+16)
    f32x4 acc[4][2];
    #pragma unroll
    for (int j = 0; j < 2; ++j)
        #pragma unroll
        for (int m = 0; m < 4; ++m)
            acc[m][j] = (f32x4){bb1[j], bb1[j], bb1[j], bb1[j]};

    #pragma unroll
    for (int kt = 0; kt < 4; ++kt) {
        bf16x8 A0 = *(const bf16x8*)&Xs[lc]     [kt * 32 + lq * 8];
        bf16x8 A1 = *(const bf16x8*)&Xs[16 + lc][kt * 32 + lq * 8];
        bf16x8 A2 = *(const bf16x8*)&Xs[32 + lc][kt * 32 + lq * 8];
        bf16x8 A3 = *(const bf16x8*)&Xs[48 + lc][kt * 32 + lq * 8];
        #pragma unroll
        for (int j = 0; j < 2; ++j) {
            acc[0][j] = __builtin_amdgcn_mfma_f32_16x16x32_bf16(A0, wf1[kt][j], acc[0][j], 0, 0, 0);
            acc[1][j] = __builtin_amdgcn_mfma_f32_16x16x32_bf16(A1, wf1[kt][j], acc[1][j], 0, 0, 0);
            acc[2][j] = __builtin_amdgcn_mfma_f32_16x16x32_bf16(A2, wf1[kt][j], acc[2][j], 0, 0, 0);
            acc[3][j] = __builtin_amdgcn_mfma_f32_16x16x32_bf16(A3, wf1[kt][j], acc[3][j], 0, 0, 0);
        }
    }

    if (isStem) {
        __syncthreads();   // all waves done reading X A-frags
        // H -> LDS (bf16, lrelu). row = m*16+lq*4+rg, col = (w*2+j)*16+lc
        #pragma unroll
        for (int j = 0; j < 2; ++j)
            #pragma unroll
            for (int m = 0; m < 4; ++m)
                #pragma unroll
                for (int rg = 0; rg < 4; ++rg)
                    Xs[m * 16 + lq * 4 + rg][(w * 2 + j) * 16 + lc] =
                        (short)f2bf(lrelu(acc[m][j][rg]));
        __syncthreads();

        // ---- layer 2: H(64x128) x W2(128x112pad) from register frags
        f32x4 acc2[4][2];
        #pragma unroll
        for (int j = 0; j < 2; ++j)
            #pragma unroll
            for (int m = 0; m < 4; ++m)
                acc2[m][j] = (f32x4){bb2[j], bb2[j], bb2[j], bb2[j]};

        #pragma unroll
        for (int kt = 0; kt < 4; ++kt) {
            bf16x8 A0 = *(const bf16x8*)&Xs[lc]     [kt * 32 + lq * 8];
            bf16x8 A1 = *(const bf16x8*)&Xs[16 + lc][kt * 32 + lq * 8];
            bf16x8 A2 = *(const bf16x8*)&Xs[32 + lc][kt * 32 + lq * 8];
            bf16x8 A3 = *(const bf16x8*)&Xs[48 + lc][kt * 32 + lq * 8];
            #pragma unroll
            for (int j = 0; j < 2; ++j) {
                acc2[0][j] = __builtin_amdgcn_mfma_f32_16x16x32_bf16(A0, wf2[kt][j], acc2[0][j], 0, 0, 0);
                acc2[1][j] = __builtin_amdgcn_mfma_f32_16x16x32_bf16(A1, wf2[kt][j], acc2[1][j], 0, 0, 0);
                acc2[2][j] = __builtin_amdgcn_mfma_f32_16x16x32_bf16(A2, wf2[kt][j], acc2[2][j], 0, 0, 0);
                acc2[3][j] = __builtin_amdgcn_mfma_f32_16x16x32_bf16(A3, wf2[kt][j], acc2[3][j], 0, 0, 0);
            }
        }
        // epilogue scatter
        #pragma unroll
        for (int m = 0; m < 4; ++m)
            #pragma unroll
            for (int rg = 0; rg < 4; ++rg) {
                int S = base + m * 16 + lq * 4 + rg;
                int gph = S / SPG, sl = S - gph * SPG;
                float* ob = out + NGRAPH + gph * COLS + 1 + 10 + sl * NOUT;
                #pragma unroll
                for (int j = 0; j < 2; ++j) {
                    int c = (w * 2 + j) * 16 + lc;
                    if (c < NOUT) ob[c] = acc2[m][j][rg];
                }
            }
    } else {
        // ---- jbond layer 2: dot over this wave's 32 cols, cross-wave reduce
        float pf[4][4];
        #pragma unroll
        for (int m = 0; m < 4; ++m)
            #pragma unroll
            for (int rg = 0; rg < 4; ++rg)
                pf[m][rg] = lrelu(acc[m][0][rg]) * wv0 + lrelu(acc[m][1][rg]) * wv1;
        #pragma unroll
        for (int off = 1; off < 16; off <<= 1)
            #pragma unroll
            for (int m = 0; m < 4; ++m)
                #pragma unroll
                for (int rg = 0; rg < 4; ++rg)
                    pf[m][rg] += __shfl_xor(pf[m][rg], off, 64);
        if (lc == 0)
            #pragma unroll
            for (int m = 0; m < 4; ++m)
                #pragma unroll
                for (int rg = 0; rg < 4; ++rg)
                    red[w][m * 16 + lq * 4 + rg] = pf[m][rg];
        __syncthreads();
        if (tid < 32) {
            int r0 = tid * 2;
            float s0 = red[0][r0] + red[1][r0] + red[2][r0] + red[3][r0];
            float s1 = red[0][r0 + 1] + red[1][r0 + 1] + red[2][r0 + 1] + red[3][r0 + 1];
            float v = (s0 + s1) * 0.5f + bj;
            int B = blk * 32 + tid;
            int g = B / 10, c = B - g * 10;
            out[NGRAPH + g * COLS + 1 + c] = v;
        }
    }
}

extern "C" void kernel_launch(void* const* d_in, const int* in_sizes, int n_in,
                              void* d_out, int out_size, void* d_ws, size_t ws_size,
                              hipStream_t stream) {
    const float* per_atom_out = (const float*)d_in[0];
    const float* scalar_outs  = (const float*)d_in[1];
    const int*   stem_atmidx  = (const int*)d_in[2];
    const int*   jbond_atmidx = (const int*)d_in[3];
    const float* W1s = (const float*)d_in[5];
    const float* b1s = (const float*)d_in[6];
    const float* W2s = (const float*)d_in[7];
    const float* b2s = (const float*)d_in[8];
    const float* W1j = (const float*)d_in[9];
    const float* b1j = (const float*)d_in[10];
    const float* W2j = (const float*)d_in[11];
    const float* b2j = (const float*)d_in[12];
    float* out = (float*)d_out;
    short* wsp = (short*)d_ws;   // needs 94208 B

    hipLaunchKernelGGL(prep_kernel, dim3(19), dim3(256), 0, stream,
                       W1s, W2s, W1j, scalar_outs, wsp, out);
    hipLaunchKernelGGL(fused_mlp, dim3(NBLK_STEM + NBLK_JB), dim3(256), 0, stream,
                       per_atom_out, stem_atmidx, jbond_atmidx, wsp,
                       b1s, b2s, b1j, W2j, b2j, out);
}

// Round 5
// 40.196 us; speedup vs baseline: 3.8587x; 1.2634x over previous
//
#include <hip/hip_runtime.h>

#define DIM 128
#define NGRAPH 4096
#define NSTEM 81920
#define NJROW 81920
#define NOUT 105
#define COLS 2111           // 1 stop + 10 break + 2100 add
#define SPG 20              // stems per graph
#define ROWS 64
#define XPAD 136            // shorts: 272B row stride; A-frag b128 reads hit the 8-word/bank floor
#define NBS 640             // stem blocks (2 tiles each)
#define NBJ 640             // jbond blocks (2 tiles each)

typedef __attribute__((ext_vector_type(8))) short bf16x8;
typedef __attribute__((ext_vector_type(4))) float f32x4;

__device__ __forceinline__ unsigned short f2bf(float f) {
    unsigned int u = __builtin_bit_cast(unsigned int, f);
    return (unsigned short)((u + 0x7fffu + ((u >> 16) & 1u)) >> 16);  // RNE
}
__device__ __forceinline__ unsigned int pk2(float x, float y) {
    return ((unsigned int)f2bf(y) << 16) | f2bf(x);
}
__device__ __forceinline__ float lrelu(float v) { return v > 0.f ? v : 0.01f * v; }

// ---- prep: pack weights to MFMA B-frag order + scalar outs. COALESCED reads
// (consecutive threads read consecutive n), scattered 2B writes (L2 absorbs).
// packed[((kt*NT+nt)*64+lane)*8+i] = bf16( W[kt*32+(lane>>4)*8+i][nt*16+(lane&15)] )
// ws layout (shorts): W1s @0 (16384), W2s @16384 (14336), W1j @30720 (16384)
__global__ __launch_bounds__(256) void prep_kernel(
    const float* __restrict__ W1s, const float* __restrict__ W2s,
    const float* __restrict__ W1j, const float* __restrict__ so,
    short* __restrict__ ws, float* __restrict__ out)
{
    int b = blockIdx.x;
    if (b < 24) {
        int mat = b >> 3, rg = b & 7;    // rg -> 16 k-rows
        const float* W; short* dst; int NT, N;
        if (mat == 0)      { W = W1s; dst = ws;         NT = 8; N = 128; }
        else if (mat == 1) { W = W2s; dst = ws + 16384; NT = 7; N = 105; }
        else               { W = W1j; dst = ws + 30720; NT = 8; N = 128; }
        int Npad = NT * 16;
        int r2 = threadIdx.x >> 7;       // 0..1
        int n  = threadIdx.x & 127;
        #pragma unroll
        for (int rr = 0; rr < 16; rr += 2) {
            int k = rg * 16 + rr + r2;
            if (n < Npad) {
                float v = (n < N) ? W[k * N + n] : 0.f;
                int kt = k >> 5, i = k & 7, sub = (k >> 3) & 3;
                int lane = sub * 16 + (n & 15), nt = n >> 4;
                dst[((kt * NT + nt) * 64 + lane) * 8 + i] = (short)f2bf(v);
            }
        }
    } else {
        int g = (b - 24) * 256 + threadIdx.x;
        if (g < NGRAPH) {
            float2 v = *(const float2*)(so + 2 * g);
            out[g] = v.x;
            out[NGRAPH + g * COLS] = v.y;
        }
    }
}

__device__ __forceinline__ void mfma_layer(const short (*X)[XPAD],
                                           const bf16x8 (&wf)[4][2],
                                           int lc, int lq, f32x4 (&acc)[4][2])
{
    #pragma unroll
    for (int kt = 0; kt < 4; ++kt) {
        bf16x8 A0 = *(const bf16x8*)&X[lc]     [kt * 32 + lq * 8];
        bf16x8 A1 = *(const bf16x8*)&X[16 + lc][kt * 32 + lq * 8];
        bf16x8 A2 = *(const bf16x8*)&X[32 + lc][kt * 32 + lq * 8];
        bf16x8 A3 = *(const bf16x8*)&X[48 + lc][kt * 32 + lq * 8];
        #pragma unroll
        for (int j = 0; j < 2; ++j) {
            acc[0][j] = __builtin_amdgcn_mfma_f32_16x16x32_bf16(A0, wf[kt][j], acc[0][j], 0, 0, 0);
            acc[1][j] = __builtin_amdgcn_mfma_f32_16x16x32_bf16(A1, wf[kt][j], acc[1][j], 0, 0, 0);
            acc[2][j] = __builtin_amdgcn_mfma_f32_16x16x32_bf16(A2, wf[kt][j], acc[2][j], 0, 0, 0);
            acc[3][j] = __builtin_amdgcn_mfma_f32_16x16x32_bf16(A3, wf[kt][j], acc[3][j], 0, 0, 0);
        }
    }
}

__device__ __forceinline__ void stage_lds(short (*X)[XPAD], int rb, int ko,
                                          const float4* g)  // g[8]: (a,b) x 4 quarters
{
    #pragma unroll
    for (int q = 0; q < 4; ++q) {
        uint4 p;
        p.x = pk2(g[2*q].x, g[2*q].y);     p.y = pk2(g[2*q].z, g[2*q].w);
        p.z = pk2(g[2*q+1].x, g[2*q+1].y); p.w = pk2(g[2*q+1].z, g[2*q+1].w);
        *(uint4*)&X[q * 16 + rb][ko] = p;
    }
}

// ---- fused stem+jbond MLP, 2 tiles/block software-pipelined.
__global__ __launch_bounds__(256, 2) void fused_mlp(
    const float* __restrict__ atom,
    const int* __restrict__ sidx, const int* __restrict__ jidx,
    const short* __restrict__ wsp,
    const float* __restrict__ b1s, const float* __restrict__ b2s,
    const float* __restrict__ b1j,
    const float* __restrict__ W2j, const float* __restrict__ b2j,
    float* __restrict__ out)
{
    __shared__ short Xs[2][ROWS][XPAD];
    __shared__ float red[4][ROWS];
    const int tid = threadIdx.x;
    const bool isStem = blockIdx.x < NBS;
    const int pb = isStem ? blockIdx.x : blockIdx.x - NBS;
    const int w = tid >> 6, l = tid & 63;
    const int lq = l >> 4, lc = l & 15;
    const int rb = tid >> 4, ko = (tid & 15) * 8;

    const int*   idx = isStem ? sidx : jidx;
    const short* W1p = isStem ? wsp : wsp + 30720;
    const float* b1  = isStem ? b1s : b1j;
    const int base0 = pb * 2 * ROWS;
    const int base1 = base0 + ROWS;

    // (1) indices for both tiles
    int a0[4], a1[4];
    #pragma unroll
    for (int q = 0; q < 4; ++q) { a0[q] = idx[base0 + q * 16 + rb]; a1[q] = idx[base1 + q * 16 + rb]; }

    // (2) gathers: both tiles issued up-front (tile1 latency hides under tile0 compute)
    float4 g0[8], g1[8];
    #pragma unroll
    for (int q = 0; q < 4; ++q) {
        g0[2*q]   = *(const float4*)(atom + a0[q] * DIM + ko);
        g0[2*q+1] = *(const float4*)(atom + a0[q] * DIM + ko + 4);
    }
    #pragma unroll
    for (int q = 0; q < 4; ++q) {
        g1[2*q]   = *(const float4*)(atom + a1[q] * DIM + ko);
        g1[2*q+1] = *(const float4*)(atom + a1[q] * DIM + ko + 4);
    }

    // (3) weights/biases (L2-hot, complete under gather latency)
    bf16x8 wf1[4][2];
    #pragma unroll
    for (int kt = 0; kt < 4; ++kt)
        #pragma unroll
        for (int j = 0; j < 2; ++j)
            wf1[kt][j] = *(const bf16x8*)(W1p + ((kt * 8 + w * 2 + j) * 64 + l) * 8);
    float bb1[2];
    #pragma unroll
    for (int j = 0; j < 2; ++j) bb1[j] = b1[(w * 2 + j) * 16 + lc];

    bf16x8 wf2[4][2];
    float bb2[2];
    float wv0 = 0.f, wv1 = 0.f, bj = 0.f;
    if (isStem) {
        const short* W2p = wsp + 16384;
        #pragma unroll
        for (int kt = 0; kt < 4; ++kt)
            #pragma unroll
            for (int j = 0; j < 2; ++j) {
                int nt = w * 2 + j; if (nt > 6) nt = 6;   // clamp; results masked
                wf2[kt][j] = *(const bf16x8*)(W2p + ((kt * 7 + nt) * 64 + l) * 8);
            }
        #pragma unroll
        for (int j = 0; j < 2; ++j) {
            int c = (w * 2 + j) * 16 + lc;
            bb2[j] = (c < NOUT) ? b2s[c] : 0.f;
        }
    } else {
        wv0 = W2j[(w * 2) * 16 + lc];
        wv1 = W2j[(w * 2 + 1) * 16 + lc];
        bj  = b2j[0];
    }

    // (4) stage tile0
    stage_lds(Xs[0], rb, ko, g0);
    __syncthreads();                                   // #1

    if (isStem) {
        #pragma unroll
        for (int tt = 0; tt < 2; ++tt) {
            f32x4 acc[4][2];
            #pragma unroll
            for (int j = 0; j < 2; ++j)
                #pragma unroll
                for (int m = 0; m < 4; ++m)
                    acc[m][j] = (f32x4){bb1[j], bb1[j], bb1[j], bb1[j]};
            mfma_layer(Xs[tt], wf1, lc, lq, acc);
            if (tt == 0) stage_lds(Xs[1], rb, ko, g1); // overlap: different buffer
            __syncthreads();                           // all done reading Xs[tt] as X
            // H -> Xs[tt] (bf16, lrelu). row = m*16+lq*4+rg, col = (w*2+j)*16+lc
            #pragma unroll
            for (int j = 0; j < 2; ++j)
                #pragma unroll
                for (int m = 0; m < 4; ++m)
                    #pragma unroll
                    for (int rg = 0; rg < 4; ++rg)
                        Xs[tt][m * 16 + lq * 4 + rg][(w * 2 + j) * 16 + lc] =
                            (short)f2bf(lrelu(acc[m][j][rg]));
            __syncthreads();

            f32x4 acc2[4][2];
            #pragma unroll
            for (int j = 0; j < 2; ++j)
                #pragma unroll
                for (int m = 0; m < 4; ++m)
                    acc2[m][j] = (f32x4){bb2[j], bb2[j], bb2[j], bb2[j]};
            mfma_layer(Xs[tt], wf2, lc, lq, acc2);

            const int baseS = base0 + tt * ROWS;
            #pragma unroll
            for (int m = 0; m < 4; ++m)
                #pragma unroll
                for (int rg = 0; rg < 4; ++rg) {
                    int S = baseS + m * 16 + lq * 4 + rg;
                    int gph = S / SPG, sl = S - gph * SPG;
                    float* ob = out + NGRAPH + gph * COLS + 1 + 10 + sl * NOUT;
                    #pragma unroll
                    for (int j = 0; j < 2; ++j) {
                        int c = (w * 2 + j) * 16 + lc;
                        if (c < NOUT) ob[c] = acc2[m][j][rg];
                    }
                }
            // no extra barrier: next iteration reads Xs[1], already fenced by the
            // two syncs above since stage of Xs[1] happened before them.
        }
    } else {
        #pragma unroll
        for (int tt = 0; tt < 2; ++tt) {
            f32x4 acc[4][2];
            #pragma unroll
            for (int j = 0; j < 2; ++j)
                #pragma unroll
                for (int m = 0; m < 4; ++m)
                    acc[m][j] = (f32x4){bb1[j], bb1[j], bb1[j], bb1[j]};
            mfma_layer(Xs[tt], wf1, lc, lq, acc);
            if (tt == 0) stage_lds(Xs[1], rb, ko, g1);

            float pf[4][4];
            #pragma unroll
            for (int m = 0; m < 4; ++m)
                #pragma unroll
                for (int rg = 0; rg < 4; ++rg)
                    pf[m][rg] = lrelu(acc[m][0][rg]) * wv0 + lrelu(acc[m][1][rg]) * wv1;
            #pragma unroll
            for (int off = 1; off < 16; off <<= 1)
                #pragma unroll
                for (int m = 0; m < 4; ++m)
                    #pragma unroll
                    for (int rg = 0; rg < 4; ++rg)
                        pf[m][rg] += __shfl_xor(pf[m][rg], off, 64);
            if (lc == 0)
                #pragma unroll
                for (int m = 0; m < 4; ++m)
                    #pragma unroll
                    for (int rg = 0; rg < 4; ++rg)
                        red[w][m * 16 + lq * 4 + rg] = pf[m][rg];
            __syncthreads();                           // red ready (+ fences Xs[1] stage)
            if (tid < 32) {
                int r0 = tid * 2;
                float s0 = red[0][r0] + red[1][r0] + red[2][r0] + red[3][r0];
                float s1 = red[0][r0+1] + red[1][r0+1] + red[2][r0+1] + red[3][r0+1];
                float v = (s0 + s1) * 0.5f + bj;
                int B = (pb * 2 + tt) * 32 + tid;
                int g = B / 10, c = B - g * 10;
                out[NGRAPH + g * COLS + 1 + c] = v;
            }
            __syncthreads();                           // red reads done before reuse
        }
    }
}

extern "C" void kernel_launch(void* const* d_in, const int* in_sizes, int n_in,
                              void* d_out, int out_size, void* d_ws, size_t ws_size,
                              hipStream_t stream) {
    const float* per_atom_out = (const float*)d_in[0];
    const float* scalar_outs  = (const float*)d_in[1];
    const int*   stem_atmidx  = (const int*)d_in[2];
    const int*   jbond_atmidx = (const int*)d_in[3];
    const float* W1s = (const float*)d_in[5];
    const float* b1s = (const float*)d_in[6];
    const float* W2s = (const float*)d_in[7];
    const float* b2s = (const float*)d_in[8];
    const float* W1j = (const float*)d_in[9];
    const float* b1j = (const float*)d_in[10];
    const float* W2j = (const float*)d_in[11];
    const float* b2j = (const float*)d_in[12];
    float* out = (float*)d_out;
    short* wsp = (short*)d_ws;   // needs 94208 B

    hipLaunchKernelGGL(prep_kernel, dim3(40), dim3(256), 0, stream,
                       W1s, W2s, W1j, scalar_outs, wsp, out);
    hipLaunchKernelGGL(fused_mlp, dim3(NBS + NBJ), dim3(256), 0, stream,
                       per_atom_out, stem_atmidx, jbond_atmidx, wsp,
                       b1s, b2s, b1j, W2j, b2j, out);
}

// Round 6
// 34.554 us; speedup vs baseline: 4.4887x; 1.1633x over previous
//
#include <hip/hip_runtime.h>

#define DIM 128
#define NGRAPH 4096
#define NSTEM 81920
#define NJROW 81920
#define NOUT 105
#define COLS 2111           // 1 stop + 10 break + 2100 add
#define SPG 20              // stems per graph
#define ROWS 64
#define XPAD 136            // shorts: 272B row stride
#define TT 4                // tiles per block
#define NBSB 320            // stem blocks  (320*4*64 = 81920 rows)
#define NBJB 320            // jbond blocks

typedef __attribute__((ext_vector_type(8))) short bf16x8;
typedef __attribute__((ext_vector_type(4))) float f32x4;

__device__ __forceinline__ unsigned short f2bf(float f) {
    unsigned int u = __builtin_bit_cast(unsigned int, f);
    return (unsigned short)((u + 0x7fffu + ((u >> 16) & 1u)) >> 16);  // RNE
}
__device__ __forceinline__ unsigned int pk2(float x, float y) {
    return ((unsigned int)f2bf(y) << 16) | f2bf(x);
}
__device__ __forceinline__ float lrelu(float v) { return v > 0.f ? v : 0.01f * v; }

// ---- prep: pack weights to MFMA B-frag order + scalar outs. Coalesced reads.
// packed[((kt*NT+nt)*64+lane)*8+i] = bf16( W[kt*32+(lane>>4)*8+i][nt*16+(lane&15)] )
// ws layout (shorts): W1s @0 (16384), W2s @16384 (14336), W1j @30720 (16384)
__global__ __launch_bounds__(256) void prep_kernel(
    const float* __restrict__ W1s, const float* __restrict__ W2s,
    const float* __restrict__ W1j, const float* __restrict__ so,
    short* __restrict__ ws, float* __restrict__ out)
{
    int b = blockIdx.x;
    if (b < 24) {
        int mat = b >> 3, rg = b & 7;    // rg -> 16 k-rows
        const float* W; short* dst; int NT, N;
        if (mat == 0)      { W = W1s; dst = ws;         NT = 8; N = 128; }
        else if (mat == 1) { W = W2s; dst = ws + 16384; NT = 7; N = 105; }
        else               { W = W1j; dst = ws + 30720; NT = 8; N = 128; }
        int Npad = NT * 16;
        int r2 = threadIdx.x >> 7;       // 0..1
        int n  = threadIdx.x & 127;
        #pragma unroll
        for (int rr = 0; rr < 16; rr += 2) {
            int k = rg * 16 + rr + r2;
            if (n < Npad) {
                float v = (n < N) ? W[k * N + n] : 0.f;
                int kt = k >> 5, i = k & 7, sub = (k >> 3) & 3;
                int lane = sub * 16 + (n & 15), nt = n >> 4;
                dst[((kt * NT + nt) * 64 + lane) * 8 + i] = (short)f2bf(v);
            }
        }
    } else {
        int g = (b - 24) * 256 + threadIdx.x;
        if (g < NGRAPH) {
            float2 v = *(const float2*)(so + 2 * g);
            out[g] = v.x;
            out[NGRAPH + g * COLS] = v.y;
        }
    }
}

__device__ __forceinline__ void mfma_layer(const short (*X)[XPAD],
                                           const bf16x8 (&wf)[4][2],
                                           int lc, int lq, f32x4 (&acc)[4][2])
{
    #pragma unroll
    for (int kt = 0; kt < 4; ++kt) {
        bf16x8 A0 = *(const bf16x8*)&X[lc]     [kt * 32 + lq * 8];
        bf16x8 A1 = *(const bf16x8*)&X[16 + lc][kt * 32 + lq * 8];
        bf16x8 A2 = *(const bf16x8*)&X[32 + lc][kt * 32 + lq * 8];
        bf16x8 A3 = *(const bf16x8*)&X[48 + lc][kt * 32 + lq * 8];
        #pragma unroll
        for (int j = 0; j < 2; ++j) {
            acc[0][j] = __builtin_amdgcn_mfma_f32_16x16x32_bf16(A0, wf[kt][j], acc[0][j], 0, 0, 0);
            acc[1][j] = __builtin_amdgcn_mfma_f32_16x16x32_bf16(A1, wf[kt][j], acc[1][j], 0, 0, 0);
            acc[2][j] = __builtin_amdgcn_mfma_f32_16x16x32_bf16(A2, wf[kt][j], acc[2][j], 0, 0, 0);
            acc[3][j] = __builtin_amdgcn_mfma_f32_16x16x32_bf16(A3, wf[kt][j], acc[3][j], 0, 0, 0);
        }
    }
}

__device__ __forceinline__ void issue_gather(const float* __restrict__ atom,
                                             const int (&a)[4], int ko, float4 (&g)[8])
{
    #pragma unroll
    for (int q = 0; q < 4; ++q) {
        g[2*q]   = *(const float4*)(atom + a[q] * DIM + ko);
        g[2*q+1] = *(const float4*)(atom + a[q] * DIM + ko + 4);
    }
}

__device__ __forceinline__ void stage_lds(short (*X)[XPAD], int rb, int ko,
                                          const float4 (&g)[8])
{
    #pragma unroll
    for (int q = 0; q < 4; ++q) {
        uint4 p;
        p.x = pk2(g[2*q].x, g[2*q].y);     p.y = pk2(g[2*q].z, g[2*q].w);
        p.z = pk2(g[2*q+1].x, g[2*q+1].y); p.w = pk2(g[2*q+1].z, g[2*q+1].w);
        *(uint4*)&X[q * 16 + rb][ko] = p;
    }
}

// ---- fused stem+jbond MLP: 4 tiles/block, rolling 1-deep gather prefetch,
// 3-buffer LDS (X dbuf + H buf) -> 2 barriers/tile.
__global__ __launch_bounds__(256, 2) void fused_mlp(
    const float* __restrict__ atom,
    const int* __restrict__ sidx, const int* __restrict__ jidx,
    const short* __restrict__ wsp,
    const float* __restrict__ b1s, const float* __restrict__ b2s,
    const float* __restrict__ b1j,
    const float* __restrict__ W2j, const float* __restrict__ b2j,
    float* __restrict__ out)
{
    __shared__ short Xbuf[2][ROWS][XPAD];
    __shared__ short Hbuf[ROWS][XPAD];
    __shared__ float red[4][ROWS];
    const int tid = threadIdx.x;
    const bool isStem = blockIdx.x < NBSB;
    const int pb = isStem ? blockIdx.x : blockIdx.x - NBSB;
    const int w = tid >> 6, l = tid & 63;
    const int lq = l >> 4, lc = l & 15;
    const int rb = tid >> 4, ko = (tid & 15) * 8;

    const int*   idx = isStem ? sidx : jidx;
    const short* W1p = isStem ? wsp : wsp + 30720;
    const float* b1  = isStem ? b1s : b1j;
    const int tbase = pb * TT * ROWS;

    // all tile indices up front (16 regs)
    int a[TT][4];
    #pragma unroll
    for (int t = 0; t < TT; ++t)
        #pragma unroll
        for (int q = 0; q < 4; ++q)
            a[t][q] = idx[tbase + t * ROWS + q * 16 + rb];

    // gather tile0, weights/biases under its latency
    float4 g[8];
    issue_gather(atom, a[0], ko, g);

    bf16x8 wf1[4][2];
    #pragma unroll
    for (int kt = 0; kt < 4; ++kt)
        #pragma unroll
        for (int j = 0; j < 2; ++j)
            wf1[kt][j] = *(const bf16x8*)(W1p + ((kt * 8 + w * 2 + j) * 64 + l) * 8);
    float bb1[2];
    #pragma unroll
    for (int j = 0; j < 2; ++j) bb1[j] = b1[(w * 2 + j) * 16 + lc];

    bf16x8 wf2[4][2];
    float bb2[2];
    float wv0 = 0.f, wv1 = 0.f, bj = 0.f;
    if (isStem) {
        const short* W2p = wsp + 16384;
        #pragma unroll
        for (int kt = 0; kt < 4; ++kt)
            #pragma unroll
            for (int j = 0; j < 2; ++j) {
                int nt = w * 2 + j; if (nt > 6) nt = 6;   // clamp; results masked
                wf2[kt][j] = *(const bf16x8*)(W2p + ((kt * 7 + nt) * 64 + l) * 8);
            }
        #pragma unroll
        for (int j = 0; j < 2; ++j) {
            int c = (w * 2 + j) * 16 + lc;
            bb2[j] = (c < NOUT) ? b2s[c] : 0.f;
        }
    } else {
        wv0 = W2j[(w * 2) * 16 + lc];
        wv1 = W2j[(w * 2 + 1) * 16 + lc];
        bj  = b2j[0];
    }

    stage_lds(Xbuf[0], rb, ko, g);
    __syncthreads();

    if (isStem) {
        #pragma unroll
        for (int t = 0; t < TT; ++t) {
            // prefetch next tile (WAR on g: stage of tile t read g before beta_{t-1})
            if (t + 1 < TT) issue_gather(atom, a[t + 1], ko, g);

            f32x4 acc[4][2];
            #pragma unroll
            for (int j = 0; j < 2; ++j)
                #pragma unroll
                for (int m = 0; m < 4; ++m)
                    acc[m][j] = (f32x4){bb1[j], bb1[j], bb1[j], bb1[j]};
            mfma_layer(Xbuf[t & 1], wf1, lc, lq, acc);

            // H -> Hbuf (prev tile's L2 reads fenced by beta). No X-read barrier needed.
            #pragma unroll
            for (int j = 0; j < 2; ++j)
                #pragma unroll
                for (int m = 0; m < 4; ++m)
                    #pragma unroll
                    for (int rg = 0; rg < 4; ++rg)
                        Hbuf[m * 16 + lq * 4 + rg][(w * 2 + j) * 16 + lc] =
                            (short)f2bf(lrelu(acc[m][j][rg]));
            __syncthreads();                       // alpha: H ready

            f32x4 acc2[4][2];
            #pragma unroll
            for (int j = 0; j < 2; ++j)
                #pragma unroll
                for (int m = 0; m < 4; ++m)
                    acc2[m][j] = (f32x4){bb2[j], bb2[j], bb2[j], bb2[j]};
            mfma_layer(Hbuf, wf2, lc, lq, acc2);

            // stage next X (its last readers, L1_{t-1}, fenced by alpha_{t-1})
            if (t + 1 < TT) stage_lds(Xbuf[(t + 1) & 1], rb, ko, g);

            const int baseS = tbase + t * ROWS;
            #pragma unroll
            for (int m = 0; m < 4; ++m)
                #pragma unroll
                for (int rg = 0; rg < 4; ++rg) {
                    int S = baseS + m * 16 + lq * 4 + rg;
                    int gph = S / SPG, sl = S - gph * SPG;
                    float* ob = out + NGRAPH + gph * COLS + 1 + 10 + sl * NOUT;
                    #pragma unroll
                    for (int j = 0; j < 2; ++j) {
                        int c = (w * 2 + j) * 16 + lc;
                        if (c < NOUT) ob[c] = acc2[m][j][rg];
                    }
                }
            __syncthreads();                       // beta: Xnext ready, H reads done
        }
    } else {
        #pragma unroll
        for (int t = 0; t < TT; ++t) {
            if (t + 1 < TT) issue_gather(atom, a[t + 1], ko, g);

            f32x4 acc[4][2];
            #pragma unroll
            for (int j = 0; j < 2; ++j)
                #pragma unroll
                for (int m = 0; m < 4; ++m)
                    acc[m][j] = (f32x4){bb1[j], bb1[j], bb1[j], bb1[j]};
            mfma_layer(Xbuf[t & 1], wf1, lc, lq, acc);

            float pf[4][4];
            #pragma unroll
            for (int m = 0; m < 4; ++m)
                #pragma unroll
                for (int rg = 0; rg < 4; ++rg)
                    pf[m][rg] = lrelu(acc[m][0][rg]) * wv0 + lrelu(acc[m][1][rg]) * wv1;
            #pragma unroll
            for (int off = 1; off < 16; off <<= 1)
                #pragma unroll
                for (int m = 0; m < 4; ++m)
                    #pragma unroll
                    for (int rg = 0; rg < 4; ++rg)
                        pf[m][rg] += __shfl_xor(pf[m][rg], off, 64);
            if (lc == 0)
                #pragma unroll
                for (int m = 0; m < 4; ++m)
                    #pragma unroll
                    for (int rg = 0; rg < 4; ++rg)
                        red[w][m * 16 + lq * 4 + rg] = pf[m][rg];
            __syncthreads();                       // alpha: red ready

            if (tid < 32) {
                int r0 = tid * 2;
                float s0 = red[0][r0] + red[1][r0] + red[2][r0] + red[3][r0];
                float s1 = red[0][r0+1] + red[1][r0+1] + red[2][r0+1] + red[3][r0+1];
                float v = (s0 + s1) * 0.5f + bj;
                int B = (pb * TT + t) * 32 + tid;
                int gg = B / 10, c = B - gg * 10;
                out[NGRAPH + gg * COLS + 1 + c] = v;
            }
            if (t + 1 < TT) stage_lds(Xbuf[(t + 1) & 1], rb, ko, g);
            __syncthreads();                       // beta: Xnext ready, red reads done
        }
    }
}

extern "C" void kernel_launch(void* const* d_in, const int* in_sizes, int n_in,
                              void* d_out, int out_size, void* d_ws, size_t ws_size,
                              hipStream_t stream) {
    const float* per_atom_out = (const float*)d_in[0];
    const float* scalar_outs  = (const float*)d_in[1];
    const int*   stem_atmidx  = (const int*)d_in[2];
    const int*   jbond_atmidx = (const int*)d_in[3];
    const float* W1s = (const float*)d_in[5];
    const float* b1s = (const float*)d_in[6];
    const float* W2s = (const float*)d_in[7];
    const float* b2s = (const float*)d_in[8];
    const float* W1j = (const float*)d_in[9];
    const float* b1j = (const float*)d_in[10];
    const float* W2j = (const float*)d_in[11];
    const float* b2j = (const float*)d_in[12];
    float* out = (float*)d_out;
    short* wsp = (short*)d_ws;   // needs 94208 B

    hipLaunchKernelGGL(prep_kernel, dim3(40), dim3(256), 0, stream,
                       W1s, W2s, W1j, scalar_outs, wsp, out);
    hipLaunchKernelGGL(fused_mlp, dim3(NBSB + NBJB), dim3(256), 0, stream,
                       per_atom_out, stem_atmidx, jbond_atmidx, wsp,
                       b1s, b2s, b1j, W2j, b2j, out);
}